// Round 4
// baseline (352.086 us; speedup 1.0000x reference)
//
#include <hip/hip_runtime.h>
#include <math.h>

#define NLAT 64
#define NLON 128
#define HID  256
#define NSTA 1024
#define NG   (NLAT * NLON)
#define TG   16    // grid points per pv block = MFMA M
#define SC   128   // station chunk (fallback fused kernel)
#define NCH  4     // chunks per block (fallback)
#define NGRP 16    // station groups in fallback phase A
#define TABN 2048  // even-symmetric table on [0, TABW)
#define TABW 4.5f
#define AG   8     // lons per score block
#define SCA  256   // stations per chunk in score kernel
#define NCHA 4     // chunks in score kernel

#define LOG2E 1.4426950408889634f
#define LN2   0.69314718055994531f

typedef float f32x4 __attribute__((ext_vector_type(4)));
typedef _Float16 f16x8 __attribute__((ext_vector_type(8)));

// accurate gelu for table build (A&S 7.1.26, |erf err| <= 1.5e-7)
__device__ __forceinline__ float gelu_ref(float x) {
    const float p  = 0.3275911f;
    const float a1 = 0.254829592f, a2 = -0.284496736f, a3 = 1.421413741f,
                a4 = -1.453152027f, a5 = 1.061405429f;
    float z  = x * 0.70710678118654752f;
    float az = fabsf(z);
    float t  = __builtin_amdgcn_rcpf(fmaf(p, az, 1.0f));
    float poly = fmaf(fmaf(fmaf(fmaf(a5, t, a4), t, a3), t, a2), t, a1) * t;
    float e  = __builtin_amdgcn_exp2f(az * az * -LOG2E);
    float r  = fmaf(-poly, e, 1.0f);
    float erfz = copysignf(r, z);
    float hx = 0.5f * x;
    return fmaf(hx, erfz, hx);
}

// ---- Kernel 0: feats [b][s][d] f32 -> F^T hi/lo [b][d][s] f16 (split for precision)
// block 256 additionally packs scaled score-MLP weights into wbuf.
__global__ __launch_bounds__(256)
void cvt_kernel(const float* __restrict__ feats,
                const float* __restrict__ W1, const float* __restrict__ b1,
                const float* __restrict__ W2, const float* __restrict__ b2p,
                _Float16* __restrict__ fhi, _Float16* __restrict__ flo,
                float* __restrict__ wbuf) {
    const int blk = blockIdx.x;
    if (blk == 256) {            // weight prep (1 thread, overlaps other blocks)
        if (threadIdx.x == 0) {
            const float ISCALE = (float)TABN / TABW;
            const float CELL   = TABW / (float)TABN;
            float A = 0.0f, B = 0.0f, C = 0.0f, D = b2p[0];
            for (int j = 0; j < 32; ++j) {
                float a = W1[j], b = W1[32 + j], c = W1[64 + j], d = b1[j], w2 = W2[j];
                wbuf[j * 8 + 0] = a * ISCALE;
                wbuf[j * 8 + 1] = b * ISCALE;
                wbuf[j * 8 + 2] = c * ISCALE;
                wbuf[j * 8 + 3] = d * ISCALE;
                wbuf[j * 8 + 4] = w2;
                wbuf[j * 8 + 5] = 0.5f * w2 * CELL;
                wbuf[j * 8 + 6] = 0.0f;
                wbuf[j * 8 + 7] = 0.0f;
                A = fmaf(0.5f * w2, a, A);
                B = fmaf(0.5f * w2, b, B);
                C = fmaf(0.5f * w2, c, C);
                D = fmaf(0.5f * w2, d, D);
            }
            wbuf[256] = A; wbuf[257] = B; wbuf[258] = C; wbuf[259] = D;
        }
        return;
    }
    __shared__ float tile[32][68];
    const int b  = blk >> 7;               // b(2) * st(32) * dt(4) = 256
    const int st = (blk >> 2) & 31;
    const int dt = blk & 3;
    {
        const int s  = threadIdx.x >> 3;
        const int dq = threadIdx.x & 7;
        const float* src = feats + ((size_t)(b * NSTA + st * 32 + s)) * HID + dt * 64 + dq * 8;
        float4 v0 = *(const float4*)src;
        float4 v1 = *(const float4*)(src + 4);
        *(float4*)&tile[s][dq * 8]     = v0;
        *(float4*)&tile[s][dq * 8 + 4] = v1;
    }
    __syncthreads();
    const int d  = threadIdx.x >> 2;
    const int sq = threadIdx.x & 3;
    f16x8 hi8, lo8;
#pragma unroll
    for (int k = 0; k < 8; ++k) {
        float v = tile[sq * 8 + k][d];
        _Float16 h = (_Float16)v;
        hi8[k] = h;
        lo8[k] = (_Float16)(v - (float)h);
    }
    const size_t o = ((size_t)(b * HID + dt * 64 + d)) * NSTA + st * 32 + sq * 8;
    *(f16x8*)&fhi[o] = hi8;
    *(f16x8*)&flo[o] = lo8;
}

// ============================ SPLIT PATH ============================

// ---- Kernel A: score MLP + softmax stats. No MFMA/AGPR -> 8 blocks/CU.
// One barrier per chunk: wave-shuffle max reduce + per-thread running (m, l).
// Writes raw f32 scores (softplus*mask) to sbuf; (m, l) per grid point at end.
__global__ __launch_bounds__(256, 8)
void score_kernel(const float* __restrict__ coords,  // [2][1024][3]
                  const float* __restrict__ maskp,   // [2][1024]
                  const float* __restrict__ wbuf,    // packed weights
                  float* __restrict__ sbuf,          // [2][8192][1024] f32
                  float* __restrict__ mout,          // [2][8192]
                  float* __restrict__ lout)          // [2][8192]
{
    __shared__ float gtab[TABN];           // 8 KB
    __shared__ float4 wpk[32];             // weights in LDS (in-order lgkmcnt!)
    __shared__ float2 w2pk[32];
    __shared__ float wmax[2][4][AG];       // double-buffered per-wave chunk maxes
    __shared__ float lred[32][AG];

    const int tid  = threadIdx.x;
    const int b    = blockIdx.x >> 10;     // 2048 blocks = 2 b * 1024 tiles
    const int tile = blockIdx.x & 1023;
    const int g0   = tile * AG;            // 8 lons, never crosses a lat row
    const int lat  = g0 >> 7;
    const float latv = -90.0f + (180.0f / 63.0f) * (float)lat;

    const float CELL = TABW / (float)TABN;
#pragma unroll
    for (int k = tid; k < TABN; k += 256) {
        float x = ((float)k + 0.5f) * CELL;
        gtab[k] = gelu_ref(-x);
    }
    if (tid < 32) {
        wpk[tid]  = *(const float4*)&wbuf[tid * 8];
        w2pk[tid] = *(const float2*)&wbuf[tid * 8 + 4];
    }
    const f32x4 lin = *(const f32x4*)&wbuf[256];
    const float LIM = (float)TABN - 0.5f;

    const int gA   = tid & (AG - 1);
    const int sgrp = tid >> 3;             // 0..31, 8 stations each
    const int lane = tid & 63;
    const int wv   = tid >> 6;
    const float lonvA = -180.0f + (360.0f / 127.0f) * (float)((g0 & 127) + gA);

    const float* cbase = coords + (size_t)b * NSTA * 3;
    const float* mbase = maskp  + (size_t)b * NSTA;
    float* srow = sbuf + ((size_t)(b * NG + g0 + gA)) * NSTA;

    float m_t = -1.0e30f, l_t = 0.0f;
    __syncthreads();   // gtab/weights ready

    for (int c = 0; c < NCHA; ++c) {
        const int sb = c * SCA + sgrp * 8;

        // scores for 8 stations at grid col gA (LUT gelu, relu-folded, exact)
        float dist[8], dla_[8], dlo_[8], v[8];
#pragma unroll
        for (int i = 0; i < 8; ++i) {
            const int s = sb + i;
            float sla = cbase[(size_t)s * 3 + 0];
            float slo = cbase[(size_t)s * 3 + 1];
            float dla = sla - latv;
            float dlo = slo - lonvA;
            dla_[i] = dla;
            dlo_[i] = dlo;
            float dss = sqrtf(fmaf(dla, dla, fmaf(dlo, dlo, 1e-6f)));
            dist[i] = dss;
            v[i] = fmaf(lin.x, dss, fmaf(lin.y, dla, fmaf(lin.z, dlo, lin.w)));
        }
#pragma unroll 2
        for (int j = 0; j < 32; ++j) {
            const float4 wq = wpk[j];
            const float2 wp = w2pk[j];
#pragma unroll
            for (int i = 0; i < 8; ++i) {
                float pre = fmaf(wq.x, dist[i], fmaf(wq.y, dla_[i], fmaf(wq.z, dlo_[i], wq.w)));
                v[i] = fmaf(wp.y, fabsf(pre), v[i]);
                float a = fminf(fabsf(pre), LIM);
                v[i] = fmaf(wp.x, gtab[(unsigned)a], v[i]);
            }
        }
        float lmax = -3.0e38f;
#pragma unroll
        for (int i = 0; i < 8; ++i) {
            float x  = v[i];
            float ax = fabsf(x);
            float e  = __builtin_amdgcn_exp2f(-ax * LOG2E);
            float sp = fmaxf(x, 0.0f) + __builtin_amdgcn_logf(1.0f + e) * LN2;
            v[i] = sp * mbase[sb + i];
            lmax = fmaxf(lmax, v[i]);
        }
        // raw scores to global (exact f32; pv recomputes p with FINAL m)
        f32x4 st0 = {v[0], v[1], v[2], v[3]};
        f32x4 st1 = {v[4], v[5], v[6], v[7]};
        *(f32x4*)(srow + sb)     = st0;
        *(f32x4*)(srow + sb + 4) = st1;

        // wave max over the wave's 8 sgrps (lane bits 3..5)
        float wm = lmax;
        wm = fmaxf(wm, __shfl_xor(wm, 8, 64));
        wm = fmaxf(wm, __shfl_xor(wm, 16, 64));
        wm = fmaxf(wm, __shfl_xor(wm, 32, 64));
        if (lane < AG) wmax[c & 1][wv][lane] = wm;
        __syncthreads();   // the one barrier per chunk (2-slot rotation is race-free)

        float mnew = m_t;
#pragma unroll
        for (int w = 0; w < 4; ++w) mnew = fmaxf(mnew, wmax[c & 1][w][gA]);
        float alpha = __builtin_amdgcn_exp2f((m_t - mnew) * LOG2E);
        m_t = mnew;
        float ps = 0.0f;
#pragma unroll
        for (int i = 0; i < 8; ++i) ps += __builtin_amdgcn_exp2f((v[i] - mnew) * LOG2E);
        l_t = l_t * alpha + ps;
    }

    lred[sgrp][gA] = l_t;
    __syncthreads();
    if (tid < AG) {       // gA == tid, m_t identical across sgrps for a given gA
        float t = 0.0f;
#pragma unroll
        for (int k = 0; k < 32; ++k) t += lred[k][tid];
        mout[b * NG + g0 + tid] = m_t;
        lout[b * NG + g0 + tid] = t;
    }
}

// ---- Kernel B: barrier-free streaming GEMM. p = exp2(s - m_final) built
// in-register as the MFMA A-fragment (hi/lo f16); no rescaling (m is final);
// epilogue normalizes by 1/l.
__global__ __launch_bounds__(256, 4)
void pv_kernel(const float* __restrict__ sbuf,     // [2][8192][1024]
               const float* __restrict__ mout,     // [2][8192]
               const float* __restrict__ lout,     // [2][8192]
               const _Float16* __restrict__ fhi,   // [2][256][1024]
               const _Float16* __restrict__ flo,
               float* __restrict__ out)            // [2][256][8192]
{
    const int b    = blockIdx.x >> 9;      // 1024 blocks = 2 b * 512 tiles
    const int tile = blockIdx.x & 511;
    const int g0   = tile * TG;
    const int tid  = threadIdx.x;
    const int lane = tid & 63;
    const int wv   = tid >> 6;

    const int row = lane & 15;             // A-frag row = output lon
    const int kg  = lane >> 4;             // k-subgroup
    const float mrow = mout[b * NG + g0 + row];
    const float* srow = sbuf + ((size_t)(b * NG + g0 + row)) * NSTA + kg * 8;
    const _Float16* fhb = fhi + (size_t)b * HID * NSTA;
    const _Float16* flb = flo + (size_t)b * HID * NSTA;
    const int dbase = wv * 64 + row;

    f32x4 acc[4];
#pragma unroll
    for (int t = 0; t < 4; ++t) acc[t] = (f32x4){0.0f, 0.0f, 0.0f, 0.0f};

    for (int c = 0; c < 8; ++c) {
        const int s0 = c * 128;
#pragma unroll
        for (int kc = 0; kc < 4; ++kc) {
            const int k0 = s0 + kc * 32;
            f32x4 sa = *(const f32x4*)(srow + k0);
            f32x4 sc = *(const f32x4*)(srow + k0 + 4);
            f16x8 ah, al;
#pragma unroll
            for (int e = 0; e < 4; ++e) {
                float p = __builtin_amdgcn_exp2f((sa[e] - mrow) * LOG2E);
                _Float16 h = (_Float16)p;
                ah[e] = h;
                al[e] = (_Float16)(p - (float)h);
            }
#pragma unroll
            for (int e = 0; e < 4; ++e) {
                float p = __builtin_amdgcn_exp2f((sc[e] - mrow) * LOG2E);
                _Float16 h = (_Float16)p;
                ah[4 + e] = h;
                al[4 + e] = (_Float16)(p - (float)h);
            }
            const int srw = k0 + kg * 8;
#pragma unroll
            for (int t = 0; t < 4; ++t) {
                const size_t off = (size_t)(dbase + t * 16) * NSTA + srw;
                f16x8 bh = *(const f16x8*)(fhb + off);
                f16x8 bl = *(const f16x8*)(flb + off);
                acc[t] = __builtin_amdgcn_mfma_f32_16x16x32_f16(ah, bh, acc[t], 0, 0, 0);
                acc[t] = __builtin_amdgcn_mfma_f32_16x16x32_f16(ah, bl, acc[t], 0, 0, 0);
                acc[t] = __builtin_amdgcn_mfma_f32_16x16x32_f16(al, bh, acc[t], 0, 0, 0);
            }
        }
    }
    // epilogue: rows m = (lane>>4)*4+reg are lons; cols = d (lane&15)
    const int m0 = (lane >> 4) * 4;
    const float4 l4 = *(const float4*)&lout[b * NG + g0 + m0];
    const float4 rl = make_float4(1.0f / l4.x, 1.0f / l4.y, 1.0f / l4.z, 1.0f / l4.w);
#pragma unroll
    for (int t = 0; t < 4; ++t) {
        const int d = wv * 64 + t * 16 + row;
        float4 o;
        o.x = acc[t].x * rl.x;
        o.y = acc[t].y * rl.y;
        o.z = acc[t].z * rl.z;
        o.w = acc[t].w * rl.w;
        *reinterpret_cast<float4*>(out + ((size_t)(b * HID + d)) * NG + g0 + m0) = o;
    }
}

// ============================ FALLBACK PATH (round-3, ws-small) ============================

__global__ __launch_bounds__(256, 6)
void s2g_kernel(const float* __restrict__ coords, const float* __restrict__ maskp,
                const float* __restrict__ wbuf,
                const _Float16* __restrict__ fhi, const _Float16* __restrict__ flo,
                float* __restrict__ out, float* __restrict__ acc1, float2* __restrict__ ml)
{
    __shared__ float gtab[TABN];
    __shared__ __align__(16) f16x8 fragAh[256];
    __shared__ __align__(16) f16x8 fragAl[256];
    __shared__ __align__(16) float maxbuf[NGRP * TG];
    __shared__ __align__(16) float psum[NGRP * TG];
    __shared__ __align__(16) float mS[TG], lS[TG], alphaS[TG];

    const int tid  = threadIdx.x;
    const int half = blockIdx.x >> 10;
    const int b    = (blockIdx.x >> 9) & 1;
    const int blk  = blockIdx.x & 511;
    const int lat  = blk >> 3;
    const int lon0 = (blk & 7) * TG;
    const int sbase = half * (NSTA / 2);
    const float latv = -90.0f + (180.0f / 63.0f) * (float)lat;
    const float LIM  = (float)TABN - 0.5f;
    const float CELL = TABW / (float)TABN;
#pragma unroll
    for (int k = tid; k < TABN; k += 256) {
        float x = ((float)k + 0.5f) * CELL;
        gtab[k] = gelu_ref(-x);
    }
    if (tid < TG) { mS[tid] = -1.0e30f; lS[tid] = 0.0f; }
    const f32x4 lin = *(const f32x4*)&wbuf[256];
    const int gA   = tid & (TG - 1);
    const int sgrp = tid >> 4;
    const float lonvA = -180.0f + (360.0f / 127.0f) * (float)(lon0 + gA);
    const int lane = tid & 63;
    const int wv   = tid >> 6;
    f32x4 acc[4];
#pragma unroll
    for (int t = 0; t < 4; ++t) acc[t] = (f32x4){0.0f, 0.0f, 0.0f, 0.0f};
    const float* cbase = coords + (size_t)b * NSTA * 3;
    const float* mbase = maskp  + (size_t)b * NSTA;
    const _Float16* fhb = fhi + (size_t)b * HID * NSTA;
    const _Float16* flb = flo + (size_t)b * HID * NSTA;
    __syncthreads();
    for (int c = 0; c < NCH; ++c) {
        const int s0 = sbase + c * SC;
        float dist[8], dlat[8], dlon[8], v[8];
#pragma unroll
        for (int i = 0; i < 8; ++i) {
            const int s = s0 + sgrp * 8 + i;
            float dla = cbase[(size_t)s * 3 + 0] - latv;
            float dlo = cbase[(size_t)s * 3 + 1] - lonvA;
            dlat[i] = dla; dlon[i] = dlo;
            float dss = sqrtf(fmaf(dla, dla, fmaf(dlo, dlo, 1e-6f)));
            dist[i] = dss;
            v[i] = fmaf(lin.x, dss, fmaf(lin.y, dla, fmaf(lin.z, dlo, lin.w)));
        }
#pragma unroll 2
        for (int j = 0; j < 32; ++j) {
            const f32x4 wq = *(const f32x4*)&wbuf[j * 8];
            const float2 wp = *(const float2*)&wbuf[j * 8 + 4];
#pragma unroll
            for (int i = 0; i < 8; ++i) {
                float pre = fmaf(wq.x, dist[i], fmaf(wq.y, dlat[i], fmaf(wq.z, dlon[i], wq.w)));
                v[i] = fmaf(wp.y, fabsf(pre), v[i]);
                float a = fminf(fabsf(pre), LIM);
                v[i] = fmaf(wp.x, gtab[(unsigned)a], v[i]);
            }
        }
        float lmax = -3.0e38f;
#pragma unroll
        for (int i = 0; i < 8; ++i) {
            const int s = s0 + sgrp * 8 + i;
            float x  = v[i];
            float ax = fabsf(x);
            float e  = __builtin_amdgcn_exp2f(-ax * LOG2E);
            float sp = fmaxf(x, 0.0f) + __builtin_amdgcn_logf(1.0f + e) * LN2;
            v[i] = sp * mbase[s];
            lmax = fmaxf(lmax, v[i]);
        }
        maxbuf[sgrp * TG + gA] = lmax;
        __syncthreads();
        if (tid < TG) {
            float cm = maxbuf[tid];
#pragma unroll
            for (int k = 1; k < NGRP; ++k) cm = fmaxf(cm, maxbuf[k * TG + tid]);
            float mold = mS[tid];
            float mnew = fmaxf(mold, cm);
            alphaS[tid] = __builtin_amdgcn_exp2f((mold - mnew) * LOG2E);
            mS[tid] = mnew;
        }
        __syncthreads();
        {
            float m  = mS[gA];
            float ps = 0.0f;
            f16x8 fh, fl;
#pragma unroll
            for (int i = 0; i < 8; ++i) {
                float p = __builtin_amdgcn_exp2f((v[i] - m) * LOG2E);
                _Float16 h = (_Float16)p;
                fh[i] = h;
                fl[i] = (_Float16)(p - (float)h);
                ps += p;
            }
            const int idx = ((sgrp >> 2) << 6) + (((sgrp & 3) << 4) | gA);
            fragAh[idx] = fh;
            fragAl[idx] = fl;
            psum[sgrp * TG + gA] = ps;
        }
        __syncthreads();
        if (tid < TG) {
            float t = 0.0f;
#pragma unroll
            for (int k = 0; k < NGRP; ++k) t += psum[k * TG + tid];
            lS[tid] = lS[tid] * alphaS[tid] + t;
        }
        {
            const f32x4 al = *(const f32x4*)&alphaS[(lane >> 4) * 4];
#pragma unroll
            for (int t = 0; t < 4; ++t) acc[t] = acc[t] * al;
            const int srow = s0 + ((lane >> 4) * 8);
            const int dbase = wv * 64 + (lane & 15);
#pragma unroll
            for (int kc = 0; kc < 4; ++kc) {
                f16x8 ah = fragAh[(kc << 6) + lane];
                f16x8 al16 = fragAl[(kc << 6) + lane];
#pragma unroll
                for (int t = 0; t < 4; ++t) {
                    const size_t off = (size_t)(dbase + t * 16) * NSTA + srow + kc * 32;
                    f16x8 bh = *(const f16x8*)(fhb + off);
                    f16x8 bl = *(const f16x8*)(flb + off);
                    acc[t] = __builtin_amdgcn_mfma_f32_16x16x32_f16(ah, bh, acc[t], 0, 0, 0);
                    acc[t] = __builtin_amdgcn_mfma_f32_16x16x32_f16(ah, bl, acc[t], 0, 0, 0);
                    acc[t] = __builtin_amdgcn_mfma_f32_16x16x32_f16(al16, bh, acc[t], 0, 0, 0);
                }
            }
        }
    }
    __syncthreads();
    {
        float* dst = half ? acc1 : out;
        const int m0 = (lane >> 4) * 4;
        const size_t gbase = (size_t)lat * NLON + lon0 + m0;
#pragma unroll
        for (int t = 0; t < 4; ++t) {
            const int d = wv * 64 + t * 16 + (lane & 15);
            *reinterpret_cast<f32x4*>(dst + ((size_t)(b * HID + d)) * NG + gbase) = acc[t];
        }
        if (tid < TG)
            ml[((half << 1) + b) * NG + lat * NLON + lon0 + tid] = make_float2(mS[tid], lS[tid]);
    }
}

__global__ __launch_bounds__(256)
void comb_kernel(float* __restrict__ out, const float* __restrict__ acc1,
                 const float2* __restrict__ ml) {
    const int x    = blockIdx.x;
    const int b    = x >> 9;
    const int lat  = (x >> 3) & 63;
    const int dseg = x & 7;
    const int lon  = threadIdx.x & 127;
    const int dsub = threadIdx.x >> 7;
    const int g    = lat * NLON + lon;
    const float2 p0 = ml[b * NG + g];
    const float2 p1 = ml[(2 + b) * NG + g];
    const float M  = fmaxf(p0.x, p1.x);
    float s0 = __builtin_amdgcn_exp2f((p0.x - M) * LOG2E);
    float s1 = __builtin_amdgcn_exp2f((p1.x - M) * LOG2E);
    const float rl = 1.0f / fmaf(p0.y, s0, p1.y * s1);
    s0 *= rl; s1 *= rl;
#pragma unroll 4
    for (int k = 0; k < 16; ++k) {
        const int d = dseg * 32 + dsub + k * 2;
        const size_t o = ((size_t)(b * HID + d)) * NG + g;
        out[o] = fmaf(out[o], s0, acc1[o] * s1);
    }
}

extern "C" void kernel_launch(void* const* d_in, const int* in_sizes, int n_in,
                              void* d_out, int out_size, void* d_ws, size_t ws_size,
                              hipStream_t stream) {
    const float* feats  = (const float*)d_in[0];
    const float* coords = (const float*)d_in[1];
    const float* maskp  = (const float*)d_in[2];
    const float* W1     = (const float*)d_in[3];
    const float* b1     = (const float*)d_in[4];
    const float* W2     = (const float*)d_in[5];
    const float* b2     = (const float*)d_in[6];
    float* out          = (float*)d_out;

    _Float16* fhi = (_Float16*)d_ws;                       // 1 MB
    _Float16* flo = fhi + (size_t)2 * HID * NSTA;          // 1 MB

    // split-path layout: sbuf 64 MB @2MB, m/l 64KB each, wbuf 4KB
    const size_t off_sbuf = (size_t)2 << 20;
    const size_t off_m    = off_sbuf + (size_t)2 * NG * NSTA * 4;
    const size_t off_l    = off_m + 65536;
    const size_t off_w    = off_l + 65536;
    const size_t NEEDED   = off_w + 4096;

    if (ws_size >= NEEDED) {
        float* sbuf = (float*)((char*)d_ws + off_sbuf);
        float* mout = (float*)((char*)d_ws + off_m);
        float* lout = (float*)((char*)d_ws + off_l);
        float* wbuf = (float*)((char*)d_ws + off_w);
        hipLaunchKernelGGL(cvt_kernel, dim3(257), dim3(256), 0, stream,
                           feats, W1, b1, W2, b2, fhi, flo, wbuf);
        hipLaunchKernelGGL(score_kernel, dim3(2048), dim3(256), 0, stream,
                           coords, maskp, wbuf, sbuf, mout, lout);
        hipLaunchKernelGGL(pv_kernel, dim3(1024), dim3(256), 0, stream,
                           sbuf, mout, lout, fhi, flo, out);
    } else {
        // round-3 fused fallback (needs ~18.3 MB)
        float*  acc1 = (float*)((char*)d_ws + (size_t)2 * 1048576);
        float2* ml   = (float2*)((char*)d_ws + (size_t)2 * 1048576 + (size_t)2 * HID * NG * 4);
        float*  wbuf = (float*)((char*)d_ws + (size_t)2 * 1048576 + (size_t)2 * HID * NG * 4 + 262144);
        hipLaunchKernelGGL(cvt_kernel, dim3(257), dim3(256), 0, stream,
                           feats, W1, b1, W2, b2, fhi, flo, wbuf);
        hipLaunchKernelGGL(s2g_kernel, dim3(2048), dim3(256), 0, stream,
                           coords, maskp, wbuf, fhi, flo, out, acc1, ml);
        hipLaunchKernelGGL(comb_kernel, dim3(1024), dim3(256), 0, stream, out, acc1, ml);
    }
}

// Round 5
// 261.257 us; speedup vs baseline: 1.3477x; 1.3477x over previous
//
#include <hip/hip_runtime.h>
#include <math.h>

#define NLAT 64
#define NLON 128
#define HID  256
#define NSTA 1024
#define NG   (NLAT * NLON)
#define TG   16    // grid points (lons) per block = MFMA M
#define SC   128   // station chunk
#define NCH  4     // chunks per block (split-K: half the stations per block)
#define TABN 2048  // even-symmetric table on [0, TABW)
#define TABW 4.5f

#define LOG2E 1.4426950408889634f
#define LN2   0.69314718055994531f

typedef float f32x4 __attribute__((ext_vector_type(4)));
typedef _Float16 f16x8 __attribute__((ext_vector_type(8)));

// accurate gelu for table build (A&S 7.1.26, |erf err| <= 1.5e-7)
__device__ __forceinline__ float gelu_ref(float x) {
    const float p  = 0.3275911f;
    const float a1 = 0.254829592f, a2 = -0.284496736f, a3 = 1.421413741f,
                a4 = -1.453152027f, a5 = 1.061405429f;
    float z  = x * 0.70710678118654752f;
    float az = fabsf(z);
    float t  = __builtin_amdgcn_rcpf(fmaf(p, az, 1.0f));
    float poly = fmaf(fmaf(fmaf(fmaf(a5, t, a4), t, a3), t, a2), t, a1) * t;
    float e  = __builtin_amdgcn_exp2f(az * az * -LOG2E);
    float r  = fmaf(-poly, e, 1.0f);
    float erfz = copysignf(r, z);
    float hx = 0.5f * x;
    return fmaf(hx, erfz, hx);
}

// ---- Kernel 0: feats [b][s][d] f32 -> F^T hi/lo [b][d][s] f16 (split for precision)
// block 256 packs scaled score-MLP weights into wbuf:
//   wbuf[j*8+0..3] = W1 row quad * ISCALE (index-unit), +3 = b1*ISCALE
//   wbuf[j*8+4]    = w2_j            (table term)
//   wbuf[j*8+5]    = 0.5*w2_j*CELL   (|pre'| relu-fold term, index->real units)
//   wbuf[256..259] = (A,B,C,D) linear coeffs; D includes b2 + sum_j w2_j*g_end
__global__ __launch_bounds__(256)
void cvt_kernel(const float* __restrict__ feats,
                const float* __restrict__ W1, const float* __restrict__ b1,
                const float* __restrict__ W2, const float* __restrict__ b2p,
                _Float16* __restrict__ fhi, _Float16* __restrict__ flo,
                float* __restrict__ wbuf) {
    const int blk = blockIdx.x;
    if (blk == 256) {            // weight prep (1 thread, overlaps other blocks)
        if (threadIdx.x == 0) {
            const float ISCALE = (float)TABN / TABW;
            const float CELL   = TABW / (float)TABN;
            const float gend   = gelu_ref(-((float)TABN - 0.5f) * CELL);
            float A = 0.0f, B = 0.0f, C = 0.0f, D = b2p[0];
            for (int j = 0; j < 32; ++j) {
                float a = W1[j], b = W1[32 + j], c = W1[64 + j], d = b1[j], w2 = W2[j];
                wbuf[j * 8 + 0] = a * ISCALE;
                wbuf[j * 8 + 1] = b * ISCALE;
                wbuf[j * 8 + 2] = c * ISCALE;
                wbuf[j * 8 + 3] = d * ISCALE;
                wbuf[j * 8 + 4] = w2;
                wbuf[j * 8 + 5] = 0.5f * w2 * CELL;
                wbuf[j * 8 + 6] = 0.0f;
                wbuf[j * 8 + 7] = 0.0f;
                A = fmaf(0.5f * w2, a, A);
                B = fmaf(0.5f * w2, b, B);
                C = fmaf(0.5f * w2, c, C);
                D = fmaf(0.5f * w2, d, D);
                D = fmaf(w2, gend, D);    // fold table end-cell: gtab is stored -g_end
            }
            wbuf[256] = A; wbuf[257] = B; wbuf[258] = C; wbuf[259] = D;
        }
        return;
    }
    __shared__ float tile[32][68];
    const int b  = blk >> 7;               // b(2) * st(32) * dt(4) = 256
    const int st = (blk >> 2) & 31;
    const int dt = blk & 3;
    {
        const int s  = threadIdx.x >> 3;
        const int dq = threadIdx.x & 7;
        const float* src = feats + ((size_t)(b * NSTA + st * 32 + s)) * HID + dt * 64 + dq * 8;
        float4 v0 = *(const float4*)src;
        float4 v1 = *(const float4*)(src + 4);
        *(float4*)&tile[s][dq * 8]     = v0;
        *(float4*)&tile[s][dq * 8 + 4] = v1;
    }
    __syncthreads();
    const int d  = threadIdx.x >> 2;
    const int sq = threadIdx.x & 3;
    f16x8 hi8, lo8;
#pragma unroll
    for (int k = 0; k < 8; ++k) {
        float v = tile[sq * 8 + k][d];
        _Float16 h = (_Float16)v;
        hi8[k] = h;
        lo8[k] = (_Float16)(v - (float)h);
    }
    const size_t o = ((size_t)(b * HID + dt * 64 + d)) * NSTA + st * 32 + sq * 8;
    *(f16x8*)&fhi[o] = hi8;
    *(f16x8*)&flo[o] = lo8;
}

// ---- Main fused kernel: score MLP (LUT gelu + per-j wave-uniform far-field skip)
// + online softmax (per-thread running m,l; 2 barriers/chunk) + MFMA weighted sum.
// Station dim split across 2 blocks (flash partials), merged by comb_kernel.
__global__ __launch_bounds__(256, 6)
void s2g_kernel(const float* __restrict__ coords,  // [2][1024][3]
                const float* __restrict__ maskp,   // [2][1024]
                const float* __restrict__ wbuf,    // packed weights (see cvt)
                const _Float16* __restrict__ fhi,  // [2][256][1024]
                const _Float16* __restrict__ flo,  // [2][256][1024]
                float* __restrict__ out,           // [2][256][8192]  (half 0 partial)
                float* __restrict__ acc1,          // [2][256][8192]  (half 1 partial)
                float2* __restrict__ ml)           // [half][b][8192] (m, l)
{
    __shared__ float gtab[TABN];                   // 8 KB: gelu(-x)-g_end on [0,4.5)
    __shared__ __align__(16) f16x8 fragAh[256];    // 4 KB: P-hi in MFMA A-frag order
    __shared__ __align__(16) f16x8 fragAl[256];    // 4 KB: P-lo
    __shared__ __align__(16) float4 wpk[32];       // (a,b,c,d)*ISCALE
    __shared__ float w2t[32];                      // w2 (table term)
    __shared__ float w2h[32];                      // 0.5*w2*CELL (|pre| term)
    __shared__ __align__(16) float wmaxW[4][TG];   // per-wave per-lon chunk maxes
    __shared__ __align__(16) float alphaS[TG];     // rescale per lon (for phase C)
    __shared__ __align__(16) float lred[TG][TG + 1];

    const int tid  = threadIdx.x;
    const int half = blockIdx.x >> 10;     // station half
    const int b    = (blockIdx.x >> 9) & 1;
    const int blk  = blockIdx.x & 511;     // 64 lat * 8 lon-blocks
    const int lat  = blk >> 3;
    const int lon0 = (blk & 7) * TG;
    const int sbase = half * (NSTA / 2);

    const float latv = -90.0f + (180.0f / 63.0f) * (float)lat;
    const float LIM  = (float)TABN - 0.5f;
    const float CELL = TABW / (float)TABN;

    // even table MINUS end-cell value: clamped gather contributes exactly 0
    // (end-cell constant folded into lin.w by cvt prep) -> skip path is EXACT.
    const float gend = gelu_ref(-LIM * CELL);
#pragma unroll
    for (int k = tid; k < TABN; k += 256) {
        float x = ((float)k + 0.5f) * CELL;
        gtab[k] = gelu_ref(-x) - gend;
    }
    if (tid < 32) {
        wpk[tid] = *(const float4*)&wbuf[tid * 8];
        w2t[tid] = wbuf[tid * 8 + 4];
        w2h[tid] = wbuf[tid * 8 + 5];
    }
    const f32x4 lin = *(const f32x4*)&wbuf[256];

    // phase A mapping: thread -> (grid col gA, station group sgrp of 8)
    const int gA   = tid & (TG - 1);
    const int sgrp = tid >> 4;             // 0..15
    const float lonvA = -180.0f + (360.0f / 127.0f) * (float)(lon0 + gA);

    // phase C mapping: wave w owns d in [w*64, w*64+64)
    const int lane = tid & 63;
    const int wv   = tid >> 6;

    f32x4 acc[4];
#pragma unroll
    for (int t = 0; t < 4; ++t) acc[t] = (f32x4){0.0f, 0.0f, 0.0f, 0.0f};

    const float* cbase = coords + (size_t)b * NSTA * 3;
    const float* mbase = maskp  + (size_t)b * NSTA;
    const _Float16* fhb = fhi + (size_t)b * HID * NSTA;
    const _Float16* flb = flo + (size_t)b * HID * NSTA;

    float m_A = -1.0e30f;   // running max for lon gA (per-thread, consistent blockwide)
    float l_t = 0.0f;       // running denom partial for (gA, sgrp) slice

    __syncthreads();   // gtab / weights visible

    for (int c = 0; c < NCH; ++c) {
        const int s0 = sbase + c * SC;

        // ---- Phase A: scores for 8 stations at grid col gA.
        // v = linear-part + sum_j [ 0.5*w2*|pre| + w2*gtab'(|pre'|) ]  (relu-folded)
        float dist[8], dla_[8], dlo_[8], v[8];
#pragma unroll
        for (int i = 0; i < 8; ++i) {
            const int s = s0 + sgrp * 8 + i;
            float dla = cbase[(size_t)s * 3 + 0] - latv;   // VMEM, L1-hot
            float dlo = cbase[(size_t)s * 3 + 1] - lonvA;
            dla_[i] = dla;
            dlo_[i] = dlo;
            float dss = sqrtf(fmaf(dla, dla, fmaf(dlo, dlo, 1e-6f)));
            dist[i] = dss;
            v[i] = fmaf(lin.x, dss, fmaf(lin.y, dla, fmaf(lin.z, dlo, lin.w)));
        }
#pragma unroll 2
        for (int j = 0; j < 32; ++j) {
            const float4 wq = wpk[j];
            const float  wy = w2h[j];
            float amin = 1.0e30f;
#pragma unroll
            for (int i = 0; i < 8; ++i) {
                float pre = fmaf(wq.x, dist[i], fmaf(wq.y, dla_[i], fmaf(wq.z, dlo_[i], wq.w)));
                v[i] = fmaf(wy, fabsf(pre), v[i]);      // |pre| term (abs = free mod)
                amin = fminf(amin, fabsf(pre));
            }
            // far-field skip: if EVERY lane's 8 stations are clamped, the table
            // term is exactly 0 (gtab' end cell == 0) -> skip the gathers.
            if (__any(amin < LIM)) {
                const float w2 = w2t[j];
#pragma unroll
                for (int i = 0; i < 8; ++i) {
                    float pre = fmaf(wq.x, dist[i], fmaf(wq.y, dla_[i], fmaf(wq.z, dlo_[i], wq.w)));
                    float a = fminf(fabsf(pre), LIM);
                    v[i] = fmaf(w2, gtab[(unsigned)a], v[i]);
                }
            }
        }
        float lmax = -3.0e38f;
#pragma unroll
        for (int i = 0; i < 8; ++i) {
            const int s = s0 + sgrp * 8 + i;
            float x  = v[i];
            float ax = fabsf(x);
            float e  = __builtin_amdgcn_exp2f(-ax * LOG2E);
            float sp = fmaxf(x, 0.0f) + __builtin_amdgcn_logf(1.0f + e) * LN2;
            v[i] = sp * mbase[s];
            lmax = fmaxf(lmax, v[i]);
        }
        // wave-reduce over the wave's 4 sgrps (lane bits 4..5), publish per lon
        float wm = lmax;
        wm = fmaxf(wm, __shfl_xor(wm, 16, 64));
        wm = fmaxf(wm, __shfl_xor(wm, 32, 64));
        if (lane < TG) wmaxW[wv][lane] = wm;
        __syncthreads();   // bar1: wmaxW ready; prev phase C done with fragA/alphaS

        // every thread: chunk max for its own lon -> running max + alpha (consistent)
        float cmx = fmaxf(fmaxf(wmaxW[0][gA], wmaxW[1][gA]),
                          fmaxf(wmaxW[2][gA], wmaxW[3][gA]));
        float mnew  = fmaxf(m_A, cmx);
        float alpha = __builtin_amdgcn_exp2f((m_A - mnew) * LOG2E);
        m_A = mnew;
        if (tid < TG) alphaS[tid] = alpha;   // tid<16 has gA==tid

        // ---- B2: p = exp2(v-m) -> f16 hi+lo in A-frag layout; local denom update
        {
            float ps = 0.0f;
            f16x8 fh, fl;
#pragma unroll
            for (int i = 0; i < 8; ++i) {
                float p = __builtin_amdgcn_exp2f((v[i] - mnew) * LOG2E);
                _Float16 h = (_Float16)p;
                fh[i] = h;
                fl[i] = (_Float16)(p - (float)h);
                ps += p;
            }
            const int idx = ((sgrp >> 2) << 6) + (((sgrp & 3) << 4) | gA);
            fragAh[idx] = fh;
            fragAl[idx] = fl;
            l_t = fmaf(l_t, alpha, ps);
        }
        __syncthreads();   // bar2: fragA + alphaS ready

        // ---- Phase C: rescale accumulators (rows m = (lane>>4)*4+reg), MFMA
        {
            const f32x4 al = *(const f32x4*)&alphaS[(lane >> 4) * 4];
#pragma unroll
            for (int t = 0; t < 4; ++t) acc[t] = acc[t] * al;

            const int srow = s0 + ((lane >> 4) * 8);
            const int dbase = wv * 64 + (lane & 15);
#pragma unroll
            for (int kc = 0; kc < 4; ++kc) {
                f16x8 ah = fragAh[(kc << 6) + lane];
                f16x8 al16 = fragAl[(kc << 6) + lane];
#pragma unroll
                for (int t = 0; t < 4; ++t) {
                    const size_t off = (size_t)(dbase + t * 16) * NSTA + srow + kc * 32;
                    f16x8 bh = *(const f16x8*)(fhb + off);
                    f16x8 bl = *(const f16x8*)(flb + off);
                    acc[t] = __builtin_amdgcn_mfma_f32_16x16x32_f16(ah, bh, acc[t], 0, 0, 0);
                    acc[t] = __builtin_amdgcn_mfma_f32_16x16x32_f16(ah, bl, acc[t], 0, 0, 0);
                    acc[t] = __builtin_amdgcn_mfma_f32_16x16x32_f16(al16, bh, acc[t], 0, 0, 0);
                }
            }
        }
    }

    // ---- epilogue: reduce l across sgrps; write UNNORMALIZED partials + (m,l)
    lred[sgrp][gA] = l_t;
    __syncthreads();
    {
        float* dst = half ? acc1 : out;
        const int m0 = (lane >> 4) * 4;
        const size_t gbase = (size_t)lat * NLON + lon0 + m0;
#pragma unroll
        for (int t = 0; t < 4; ++t) {
            const int d = wv * 64 + t * 16 + (lane & 15);
            *reinterpret_cast<f32x4*>(dst + ((size_t)(b * HID + d)) * NG + gbase) = acc[t];
        }
        if (tid < TG) {
            float t = 0.0f;
#pragma unroll
            for (int k = 0; k < TG; ++k) t += lred[k][tid];
            ml[((half << 1) + b) * NG + lat * NLON + lon0 + tid] = make_float2(m_A, t);
        }
    }
}

// ---- Combine kernel: out = (acc0*e^{m0-M} + acc1*e^{m1-M}) / (l0*e^{m0-M} + l1*e^{m1-M})
__global__ __launch_bounds__(256)
void comb_kernel(float* __restrict__ out, const float* __restrict__ acc1,
                 const float2* __restrict__ ml) {
    const int x    = blockIdx.x;          // 1024 = b(2) * lat(64) * dseg(8)
    const int b    = x >> 9;
    const int lat  = (x >> 3) & 63;
    const int dseg = x & 7;               // 32 d each
    const int lon  = threadIdx.x & 127;
    const int dsub = threadIdx.x >> 7;    // 0..1
    const int g    = lat * NLON + lon;

    const float2 p0 = ml[b * NG + g];
    const float2 p1 = ml[(2 + b) * NG + g];
    const float M  = fmaxf(p0.x, p1.x);
    float s0 = __builtin_amdgcn_exp2f((p0.x - M) * LOG2E);
    float s1 = __builtin_amdgcn_exp2f((p1.x - M) * LOG2E);
    const float rl = 1.0f / fmaf(p0.y, s0, p1.y * s1);
    s0 *= rl; s1 *= rl;

#pragma unroll 4
    for (int k = 0; k < 16; ++k) {
        const int d = dseg * 32 + dsub + k * 2;
        const size_t o = ((size_t)(b * HID + d)) * NG + g;
        out[o] = fmaf(out[o], s0, acc1[o] * s1);
    }
}

extern "C" void kernel_launch(void* const* d_in, const int* in_sizes, int n_in,
                              void* d_out, int out_size, void* d_ws, size_t ws_size,
                              hipStream_t stream) {
    const float* feats  = (const float*)d_in[0];
    const float* coords = (const float*)d_in[1];
    const float* maskp  = (const float*)d_in[2];
    const float* W1     = (const float*)d_in[3];
    const float* b1     = (const float*)d_in[4];
    const float* W2     = (const float*)d_in[5];
    const float* b2     = (const float*)d_in[6];
    float* out          = (float*)d_out;

    // workspace map:
    //   fhi  [2][256][1024] f16 : 1 MB
    //   flo  [2][256][1024] f16 : 1 MB
    //   acc1 [2][256][8192] f32 : 16 MB   (half-1 partial; half-0 goes to d_out)
    //   ml   [2][2][8192] float2: 256 KB
    //   wbuf 260 floats (packed weights)
    _Float16* fhi = (_Float16*)d_ws;
    _Float16* flo = fhi + (size_t)2 * HID * NSTA;
    float*  acc1 = (float*)((char*)d_ws + (size_t)2 * 1048576);
    float2* ml   = (float2*)((char*)d_ws + (size_t)2 * 1048576 + (size_t)2 * HID * NG * 4);
    float*  wbuf = (float*)((char*)d_ws + (size_t)2 * 1048576 + (size_t)2 * HID * NG * 4 + 262144);

    hipLaunchKernelGGL(cvt_kernel, dim3(257), dim3(256), 0, stream,
                       feats, W1, b1, W2, b2, fhi, flo, wbuf);
    hipLaunchKernelGGL(s2g_kernel, dim3(2048), dim3(256), 0, stream,
                       coords, maskp, wbuf, fhi, flo, out, acc1, ml);
    hipLaunchKernelGGL(comb_kernel, dim3(1024), dim3(256), 0, stream, out, acc1, ml);
}

// Round 6
// 258.410 us; speedup vs baseline: 1.3625x; 1.0110x over previous
//
#include <hip/hip_runtime.h>
#include <math.h>

#define NLAT 64
#define NLON 128
#define HID  256
#define NSTA 1024
#define NG   (NLAT * NLON)
#define TG   16    // grid points (lons) per block = MFMA M
#define SC   128   // station chunk
#define NCH  4     // chunks per block (split-K: half the stations per block)
#define TABN 2048  // even-symmetric table on [0, TABW)
#define TABW 4.5f

#define LOG2E 1.4426950408889634f
#define LN2   0.69314718055994531f

typedef float f32x4 __attribute__((ext_vector_type(4)));
typedef _Float16 f16x8 __attribute__((ext_vector_type(8)));

// accurate gelu for table build (A&S 7.1.26, |erf err| <= 1.5e-7)
__device__ __forceinline__ float gelu_ref(float x) {
    const float p  = 0.3275911f;
    const float a1 = 0.254829592f, a2 = -0.284496736f, a3 = 1.421413741f,
                a4 = -1.453152027f, a5 = 1.061405429f;
    float z  = x * 0.70710678118654752f;
    float az = fabsf(z);
    float t  = __builtin_amdgcn_rcpf(fmaf(p, az, 1.0f));
    float poly = fmaf(fmaf(fmaf(fmaf(a5, t, a4), t, a3), t, a2), t, a1) * t;
    float e  = __builtin_amdgcn_exp2f(az * az * -LOG2E);
    float r  = fmaf(-poly, e, 1.0f);
    float erfz = copysignf(r, z);
    float hx = 0.5f * x;
    return fmaf(hx, erfz, hx);
}

// ---- Kernel 0: feats [b][s][d] f32 -> F^T hi/lo [b][d][s] f16 (split for precision)
// block 256 packs scaled score-MLP weights into wbuf:
//   wbuf[j*8+0..3] = W1 row quad * ISCALE (index-unit), +3 = b1*ISCALE
//   wbuf[j*8+4]    = w2_j            (table term)
//   wbuf[j*8+5]    = 0.5*w2_j*CELL   (|pre'| relu-fold term, index->real units)
//   wbuf[256..259] = (A,B,C,D) linear coeffs; D includes b2 + sum_j w2_j*g_end
__global__ __launch_bounds__(256)
void cvt_kernel(const float* __restrict__ feats,
                const float* __restrict__ W1, const float* __restrict__ b1,
                const float* __restrict__ W2, const float* __restrict__ b2p,
                _Float16* __restrict__ fhi, _Float16* __restrict__ flo,
                float* __restrict__ wbuf) {
    const int blk = blockIdx.x;
    if (blk == 256) {            // weight prep (1 thread, overlaps other blocks)
        if (threadIdx.x == 0) {
            const float ISCALE = (float)TABN / TABW;
            const float CELL   = TABW / (float)TABN;
            const float gend   = gelu_ref(-((float)TABN - 0.5f) * CELL);
            float A = 0.0f, B = 0.0f, C = 0.0f, D = b2p[0];
            for (int j = 0; j < 32; ++j) {
                float a = W1[j], b = W1[32 + j], c = W1[64 + j], d = b1[j], w2 = W2[j];
                wbuf[j * 8 + 0] = a * ISCALE;
                wbuf[j * 8 + 1] = b * ISCALE;
                wbuf[j * 8 + 2] = c * ISCALE;
                wbuf[j * 8 + 3] = d * ISCALE;
                wbuf[j * 8 + 4] = w2;
                wbuf[j * 8 + 5] = 0.5f * w2 * CELL;
                wbuf[j * 8 + 6] = 0.0f;
                wbuf[j * 8 + 7] = 0.0f;
                A = fmaf(0.5f * w2, a, A);
                B = fmaf(0.5f * w2, b, B);
                C = fmaf(0.5f * w2, c, C);
                D = fmaf(0.5f * w2, d, D);
                D = fmaf(w2, gend, D);    // fold table end-cell: gtab is stored -g_end
            }
            wbuf[256] = A; wbuf[257] = B; wbuf[258] = C; wbuf[259] = D;
        }
        return;
    }
    __shared__ float tile[32][68];
    const int b  = blk >> 7;               // b(2) * st(32) * dt(4) = 256
    const int st = (blk >> 2) & 31;
    const int dt = blk & 3;
    {
        const int s  = threadIdx.x >> 3;
        const int dq = threadIdx.x & 7;
        const float* src = feats + ((size_t)(b * NSTA + st * 32 + s)) * HID + dt * 64 + dq * 8;
        float4 v0 = *(const float4*)src;
        float4 v1 = *(const float4*)(src + 4);
        *(float4*)&tile[s][dq * 8]     = v0;
        *(float4*)&tile[s][dq * 8 + 4] = v1;
    }
    __syncthreads();
    const int d  = threadIdx.x >> 2;
    const int sq = threadIdx.x & 3;
    f16x8 hi8, lo8;
#pragma unroll
    for (int k = 0; k < 8; ++k) {
        float v = tile[sq * 8 + k][d];
        _Float16 h = (_Float16)v;
        hi8[k] = h;
        lo8[k] = (_Float16)(v - (float)h);
    }
    const size_t o = ((size_t)(b * HID + dt * 64 + d)) * NSTA + st * 32 + sq * 8;
    *(f16x8*)&fhi[o] = hi8;
    *(f16x8*)&flo[o] = lo8;
}

// ---- Main fused kernel: score MLP (LUT gelu + per-j wave-uniform far-field skip)
// + online softmax (per-thread running m,l; 2 barriers/chunk) + MFMA weighted sum.
// Station dim split across 2 blocks (flash partials), merged by comb_kernel.
// launch_bounds(256,4): 128 regs/wave budget (unified VGPR+AGPR). r1/r5 showed
// (256,8)/(256,6) force scratch spills INSIDE the j-loop (WRITE_SIZE +25-70 MB,
// duration pinned); measured occupancy at (256,6) was 47% anyway, so the (256,4)
// cap of 50% costs nothing and guarantees zero spill (r0: 56+16 regs fit).
__global__ __launch_bounds__(256, 4)
void s2g_kernel(const float* __restrict__ coords,  // [2][1024][3]
                const float* __restrict__ maskp,   // [2][1024]
                const float* __restrict__ wbuf,    // packed weights (see cvt)
                const _Float16* __restrict__ fhi,  // [2][256][1024]
                const _Float16* __restrict__ flo,  // [2][256][1024]
                float* __restrict__ out,           // [2][256][8192]  (half 0 partial)
                float* __restrict__ acc1,          // [2][256][8192]  (half 1 partial)
                float2* __restrict__ ml)           // [half][b][8192] (m, l)
{
    __shared__ float gtab[TABN];                   // 8 KB: gelu(-x)-g_end on [0,4.5)
    __shared__ __align__(16) f16x8 fragAh[256];    // 4 KB: P-hi in MFMA A-frag order
    __shared__ __align__(16) f16x8 fragAl[256];    // 4 KB: P-lo
    __shared__ __align__(16) float4 wpk[32];       // (a,b,c,d)*ISCALE
    __shared__ float w2t[32];                      // w2 (table term)
    __shared__ float w2h[32];                      // 0.5*w2*CELL (|pre| term)
    __shared__ __align__(16) float wmaxW[4][TG];   // per-wave per-lon chunk maxes
    __shared__ __align__(16) float alphaS[TG];     // rescale per lon (for phase C)
    __shared__ __align__(16) float lred[TG][TG + 1];

    const int tid  = threadIdx.x;
    const int half = blockIdx.x >> 10;     // station half
    const int b    = (blockIdx.x >> 9) & 1;
    const int blk  = blockIdx.x & 511;     // 64 lat * 8 lon-blocks
    const int lat  = blk >> 3;
    const int lon0 = (blk & 7) * TG;
    const int sbase = half * (NSTA / 2);

    const float latv = -90.0f + (180.0f / 63.0f) * (float)lat;
    const float LIM  = (float)TABN - 0.5f;
    const float CELL = TABW / (float)TABN;

    // even table MINUS end-cell value: clamped gather contributes exactly 0
    // (end-cell constant folded into lin.w by cvt prep) -> skip path is EXACT.
    const float gend = gelu_ref(-LIM * CELL);
#pragma unroll
    for (int k = tid; k < TABN; k += 256) {
        float x = ((float)k + 0.5f) * CELL;
        gtab[k] = gelu_ref(-x) - gend;
    }
    if (tid < 32) {
        wpk[tid] = *(const float4*)&wbuf[tid * 8];
        w2t[tid] = wbuf[tid * 8 + 4];
        w2h[tid] = wbuf[tid * 8 + 5];
    }
    const f32x4 lin = *(const f32x4*)&wbuf[256];

    // phase A mapping: thread -> (grid col gA, station group sgrp of 8)
    const int gA   = tid & (TG - 1);
    const int sgrp = tid >> 4;             // 0..15
    const float lonvA = -180.0f + (360.0f / 127.0f) * (float)(lon0 + gA);

    // phase C mapping: wave w owns d in [w*64, w*64+64)
    const int lane = tid & 63;
    const int wv   = tid >> 6;

    f32x4 acc[4];
#pragma unroll
    for (int t = 0; t < 4; ++t) acc[t] = (f32x4){0.0f, 0.0f, 0.0f, 0.0f};

    const float* cbase = coords + (size_t)b * NSTA * 3;
    const float* mbase = maskp  + (size_t)b * NSTA;
    const _Float16* fhb = fhi + (size_t)b * HID * NSTA;
    const _Float16* flb = flo + (size_t)b * HID * NSTA;

    float m_A = -1.0e30f;   // running max for lon gA (per-thread, consistent blockwide)
    float l_t = 0.0f;       // running denom partial for (gA, sgrp) slice

    __syncthreads();   // gtab / weights visible

    for (int c = 0; c < NCH; ++c) {
        const int s0 = sbase + c * SC;

        // ---- Phase A: scores for 8 stations at grid col gA.
        // v = linear-part + sum_j [ 0.5*w2*|pre| + w2*gtab'(|pre'|) ]  (relu-folded)
        float dist[8], dla_[8], dlo_[8], v[8];
#pragma unroll
        for (int i = 0; i < 8; ++i) {
            const int s = s0 + sgrp * 8 + i;
            float dla = cbase[(size_t)s * 3 + 0] - latv;   // VMEM, L1-hot
            float dlo = cbase[(size_t)s * 3 + 1] - lonvA;
            dla_[i] = dla;
            dlo_[i] = dlo;
            float dss = sqrtf(fmaf(dla, dla, fmaf(dlo, dlo, 1e-6f)));
            dist[i] = dss;
            v[i] = fmaf(lin.x, dss, fmaf(lin.y, dla, fmaf(lin.z, dlo, lin.w)));
        }
#pragma unroll 2
        for (int j = 0; j < 32; ++j) {
            const float4 wq = wpk[j];
            const float  wy = w2h[j];
            float pre[8];
            float amin = 1.0e30f;
#pragma unroll
            for (int i = 0; i < 8; ++i) {
                pre[i] = fmaf(wq.x, dist[i], fmaf(wq.y, dla_[i], fmaf(wq.z, dlo_[i], wq.w)));
                v[i] = fmaf(wy, fabsf(pre[i]), v[i]);   // |pre| term (abs = free mod)
                amin = fminf(amin, fabsf(pre[i]));
            }
            // far-field skip: if EVERY lane's 8 stations are clamped, the table
            // term is exactly 0 (gtab' end cell == 0) -> skip the gathers.
            if (__any(amin < LIM)) {
                const float w2 = w2t[j];
#pragma unroll
                for (int i = 0; i < 8; ++i) {
                    float a = fminf(fabsf(pre[i]), LIM);   // pre kept in regs (no recompute)
                    v[i] = fmaf(w2, gtab[(unsigned)a], v[i]);
                }
            }
        }
        float lmax = -3.0e38f;
#pragma unroll
        for (int i = 0; i < 8; ++i) {
            const int s = s0 + sgrp * 8 + i;
            float x  = v[i];
            float ax = fabsf(x);
            float e  = __builtin_amdgcn_exp2f(-ax * LOG2E);
            float sp = fmaxf(x, 0.0f) + __builtin_amdgcn_logf(1.0f + e) * LN2;
            v[i] = sp * mbase[s];
            lmax = fmaxf(lmax, v[i]);
        }
        // wave-reduce over the wave's 4 sgrps (lane bits 4..5), publish per lon
        float wm = lmax;
        wm = fmaxf(wm, __shfl_xor(wm, 16, 64));
        wm = fmaxf(wm, __shfl_xor(wm, 32, 64));
        if (lane < TG) wmaxW[wv][lane] = wm;
        __syncthreads();   // bar1: wmaxW ready; prev phase C done with fragA/alphaS

        // every thread: chunk max for its own lon -> running max + alpha (consistent)
        float cmx = fmaxf(fmaxf(wmaxW[0][gA], wmaxW[1][gA]),
                          fmaxf(wmaxW[2][gA], wmaxW[3][gA]));
        float mnew  = fmaxf(m_A, cmx);
        float alpha = __builtin_amdgcn_exp2f((m_A - mnew) * LOG2E);
        m_A = mnew;
        if (tid < TG) alphaS[tid] = alpha;   // tid<16 has gA==tid

        // ---- B2: p = exp2(v-m) -> f16 hi+lo in A-frag layout; local denom update
        {
            float ps = 0.0f;
            f16x8 fh, fl;
#pragma unroll
            for (int i = 0; i < 8; ++i) {
                float p = __builtin_amdgcn_exp2f((v[i] - mnew) * LOG2E);
                _Float16 h = (_Float16)p;
                fh[i] = h;
                fl[i] = (_Float16)(p - (float)h);
                ps += p;
            }
            const int idx = ((sgrp >> 2) << 6) + (((sgrp & 3) << 4) | gA);
            fragAh[idx] = fh;
            fragAl[idx] = fl;
            l_t = fmaf(l_t, alpha, ps);
        }
        __syncthreads();   // bar2: fragA + alphaS ready

        // ---- Phase C: rescale accumulators (rows m = (lane>>4)*4+reg), MFMA
        {
            const f32x4 al = *(const f32x4*)&alphaS[(lane >> 4) * 4];
#pragma unroll
            for (int t = 0; t < 4; ++t) acc[t] = acc[t] * al;

            const int srow = s0 + ((lane >> 4) * 8);
            const int dbase = wv * 64 + (lane & 15);
#pragma unroll
            for (int kc = 0; kc < 4; ++kc) {
                f16x8 ah = fragAh[(kc << 6) + lane];
                f16x8 al16 = fragAl[(kc << 6) + lane];
#pragma unroll
                for (int t = 0; t < 4; ++t) {
                    const size_t off = (size_t)(dbase + t * 16) * NSTA + srow + kc * 32;
                    f16x8 bh = *(const f16x8*)(fhb + off);
                    f16x8 bl = *(const f16x8*)(flb + off);
                    acc[t] = __builtin_amdgcn_mfma_f32_16x16x32_f16(ah, bh, acc[t], 0, 0, 0);
                    acc[t] = __builtin_amdgcn_mfma_f32_16x16x32_f16(ah, bl, acc[t], 0, 0, 0);
                    acc[t] = __builtin_amdgcn_mfma_f32_16x16x32_f16(al16, bh, acc[t], 0, 0, 0);
                }
            }
        }
    }

    // ---- epilogue: reduce l across sgrps; write UNNORMALIZED partials + (m,l)
    lred[sgrp][gA] = l_t;
    __syncthreads();
    {
        float* dst = half ? acc1 : out;
        const int m0 = (lane >> 4) * 4;
        const size_t gbase = (size_t)lat * NLON + lon0 + m0;
#pragma unroll
        for (int t = 0; t < 4; ++t) {
            const int d = wv * 64 + t * 16 + (lane & 15);
            *reinterpret_cast<f32x4*>(dst + ((size_t)(b * HID + d)) * NG + gbase) = acc[t];
        }
        if (tid < TG) {
            float t = 0.0f;
#pragma unroll
            for (int k = 0; k < TG; ++k) t += lred[k][tid];
            ml[((half << 1) + b) * NG + lat * NLON + lon0 + tid] = make_float2(m_A, t);
        }
    }
}

// ---- Combine kernel: out = (acc0*e^{m0-M} + acc1*e^{m1-M}) / (l0*e^{m0-M} + l1*e^{m1-M})
__global__ __launch_bounds__(256)
void comb_kernel(float* __restrict__ out, const float* __restrict__ acc1,
                 const float2* __restrict__ ml) {
    const int x    = blockIdx.x;          // 1024 = b(2) * lat(64) * dseg(8)
    const int b    = x >> 9;
    const int lat  = (x >> 3) & 63;
    const int dseg = x & 7;               // 32 d each
    const int lon  = threadIdx.x & 127;
    const int dsub = threadIdx.x >> 7;    // 0..1
    const int g    = lat * NLON + lon;

    const float2 p0 = ml[b * NG + g];
    const float2 p1 = ml[(2 + b) * NG + g];
    const float M  = fmaxf(p0.x, p1.x);
    float s0 = __builtin_amdgcn_exp2f((p0.x - M) * LOG2E);
    float s1 = __builtin_amdgcn_exp2f((p1.x - M) * LOG2E);
    const float rl = 1.0f / fmaf(p0.y, s0, p1.y * s1);
    s0 *= rl; s1 *= rl;

#pragma unroll 4
    for (int k = 0; k < 16; ++k) {
        const int d = dseg * 32 + dsub + k * 2;
        const size_t o = ((size_t)(b * HID + d)) * NG + g;
        out[o] = fmaf(out[o], s0, acc1[o] * s1);
    }
}

extern "C" void kernel_launch(void* const* d_in, const int* in_sizes, int n_in,
                              void* d_out, int out_size, void* d_ws, size_t ws_size,
                              hipStream_t stream) {
    const float* feats  = (const float*)d_in[0];
    const float* coords = (const float*)d_in[1];
    const float* maskp  = (const float*)d_in[2];
    const float* W1     = (const float*)d_in[3];
    const float* b1     = (const float*)d_in[4];
    const float* W2     = (const float*)d_in[5];
    const float* b2     = (const float*)d_in[6];
    float* out          = (float*)d_out;

    // workspace map:
    //   fhi  [2][256][1024] f16 : 1 MB
    //   flo  [2][256][1024] f16 : 1 MB
    //   acc1 [2][256][8192] f32 : 16 MB   (half-1 partial; half-0 goes to d_out)
    //   ml   [2][2][8192] float2: 256 KB
    //   wbuf 260 floats (packed weights)
    _Float16* fhi = (_Float16*)d_ws;
    _Float16* flo = fhi + (size_t)2 * HID * NSTA;
    float*  acc1 = (float*)((char*)d_ws + (size_t)2 * 1048576);
    float2* ml   = (float2*)((char*)d_ws + (size_t)2 * 1048576 + (size_t)2 * HID * NG * 4);
    float*  wbuf = (float*)((char*)d_ws + (size_t)2 * 1048576 + (size_t)2 * HID * NG * 4 + 262144);

    hipLaunchKernelGGL(cvt_kernel, dim3(257), dim3(256), 0, stream,
                       feats, W1, b1, W2, b2, fhi, flo, wbuf);
    hipLaunchKernelGGL(s2g_kernel, dim3(2048), dim3(256), 0, stream,
                       coords, maskp, wbuf, fhi, flo, out, acc1, ml);
    hipLaunchKernelGGL(comb_kernel, dim3(1024), dim3(256), 0, stream, out, acc1, ml);
}

// Round 8
// 254.348 us; speedup vs baseline: 1.3843x; 1.0160x over previous
//
#include <hip/hip_runtime.h>
#include <math.h>

#define NLAT 64
#define NLON 128
#define HID  256
#define NSTA 1024
#define NG   (NLAT * NLON)
#define TG   16    // grid points (lons) per block = MFMA M
#define SC   128   // station chunk
#define NCH  4     // chunks per block (split-K: half the stations per block)
#define TABN 2048  // even-symmetric table on [0, TABW)
#define TABW 4.5f

#define LOG2E 1.4426950408889634f
#define LN2   0.69314718055994531f

typedef float f32x2 __attribute__((ext_vector_type(2)));
typedef float f32x4 __attribute__((ext_vector_type(4)));
typedef _Float16 f16x8 __attribute__((ext_vector_type(8)));

// accurate gelu for table build (A&S 7.1.26, |erf err| <= 1.5e-7)
__device__ __forceinline__ float gelu_ref(float x) {
    const float p  = 0.3275911f;
    const float a1 = 0.254829592f, a2 = -0.284496736f, a3 = 1.421413741f,
                a4 = -1.453152027f, a5 = 1.061405429f;
    float z  = x * 0.70710678118654752f;
    float az = fabsf(z);
    float t  = __builtin_amdgcn_rcpf(fmaf(p, az, 1.0f));
    float poly = fmaf(fmaf(fmaf(fmaf(a5, t, a4), t, a3), t, a2), t, a1) * t;
    float e  = __builtin_amdgcn_exp2f(az * az * -LOG2E);
    float r  = fmaf(-poly, e, 1.0f);
    float erfz = copysignf(r, z);
    float hx = 0.5f * x;
    return fmaf(hx, erfz, hx);
}

// ---- Kernel 0: feats [b][s][d] f32 -> F^T hi/lo [b][d][s] f16 (split for precision)
// block 256 packs scaled score-MLP weights into wbuf (see r5 comment).
__global__ __launch_bounds__(256)
void cvt_kernel(const float* __restrict__ feats,
                const float* __restrict__ W1, const float* __restrict__ b1,
                const float* __restrict__ W2, const float* __restrict__ b2p,
                _Float16* __restrict__ fhi, _Float16* __restrict__ flo,
                float* __restrict__ wbuf) {
    const int blk = blockIdx.x;
    if (blk == 256) {            // weight prep (1 thread, overlaps other blocks)
        if (threadIdx.x == 0) {
            const float ISCALE = (float)TABN / TABW;
            const float CELL   = TABW / (float)TABN;
            const float gend   = gelu_ref(-((float)TABN - 0.5f) * CELL);
            float A = 0.0f, B = 0.0f, C = 0.0f, D = b2p[0];
            for (int j = 0; j < 32; ++j) {
                float a = W1[j], b = W1[32 + j], c = W1[64 + j], d = b1[j], w2 = W2[j];
                wbuf[j * 8 + 0] = a * ISCALE;
                wbuf[j * 8 + 1] = b * ISCALE;
                wbuf[j * 8 + 2] = c * ISCALE;
                wbuf[j * 8 + 3] = d * ISCALE;
                wbuf[j * 8 + 4] = w2;
                wbuf[j * 8 + 5] = 0.5f * w2 * CELL;
                wbuf[j * 8 + 6] = 0.0f;
                wbuf[j * 8 + 7] = 0.0f;
                A = fmaf(0.5f * w2, a, A);
                B = fmaf(0.5f * w2, b, B);
                C = fmaf(0.5f * w2, c, C);
                D = fmaf(0.5f * w2, d, D);
                D = fmaf(w2, gend, D);    // fold table end-cell: gtab is stored -g_end
            }
            wbuf[256] = A; wbuf[257] = B; wbuf[258] = C; wbuf[259] = D;
        }
        return;
    }
    __shared__ float tile[32][68];
    const int b  = blk >> 7;               // b(2) * st(32) * dt(4) = 256
    const int st = (blk >> 2) & 31;
    const int dt = blk & 3;
    {
        const int s  = threadIdx.x >> 3;
        const int dq = threadIdx.x & 7;
        const float* src = feats + ((size_t)(b * NSTA + st * 32 + s)) * HID + dt * 64 + dq * 8;
        float4 v0 = *(const float4*)src;
        float4 v1 = *(const float4*)(src + 4);
        *(float4*)&tile[s][dq * 8]     = v0;
        *(float4*)&tile[s][dq * 8 + 4] = v1;
    }
    __syncthreads();
    const int d  = threadIdx.x >> 2;
    const int sq = threadIdx.x & 3;
    f16x8 hi8, lo8;
#pragma unroll
    for (int k = 0; k < 8; ++k) {
        float v = tile[sq * 8 + k][d];
        _Float16 h = (_Float16)v;
        hi8[k] = h;
        lo8[k] = (_Float16)(v - (float)h);
    }
    const size_t o = ((size_t)(b * HID + dt * 64 + d)) * NSTA + st * 32 + sq * 8;
    *(f16x8*)&fhi[o] = hi8;
    *(f16x8*)&flo[o] = lo8;
}

// ---- Main fused kernel, software-pipelined: phase C for chunk c-1 is issued
// WITH phase A of chunk c (MFMA+VMEM overlap VALU), fragA double-buffered.
// Same 2 barriers/chunk. j-loop packed as f32x2 (v_pk_fma_f32).
__global__ __launch_bounds__(256, 4)
void s2g_kernel(const float* __restrict__ coords,  // [2][1024][3]
                const float* __restrict__ maskp,   // [2][1024]
                const float* __restrict__ wbuf,    // packed weights (see cvt)
                const _Float16* __restrict__ fhi,  // [2][256][1024]
                const _Float16* __restrict__ flo,  // [2][256][1024]
                float* __restrict__ out,           // [2][256][8192]  (half 0 partial)
                float* __restrict__ acc1,          // [2][256][8192]  (half 1 partial)
                float2* __restrict__ ml)           // [half][b][8192] (m, l)
{
    __shared__ float gtab[TABN];                     // 8 KB: gelu(-x)-g_end on [0,4.5)
    __shared__ __align__(16) f16x8 fragAh[2][256];   // 8 KB: P-hi, double-buffered
    __shared__ __align__(16) f16x8 fragAl[2][256];   // 8 KB: P-lo
    __shared__ __align__(16) float4 wpk[32];         // (a,b,c,d)*ISCALE
    __shared__ float w2t[32];                        // w2 (table term)
    __shared__ float w2h[32];                        // 0.5*w2*CELL (|pre| term)
    __shared__ __align__(16) float wmaxW[4][TG];     // per-wave per-lon chunk maxes
    __shared__ __align__(16) float alphaS[TG];       // rescale per lon (for phase C)
    __shared__ __align__(16) float lred[TG][TG + 1];

    const int tid  = threadIdx.x;
    const int half = blockIdx.x >> 10;     // station half
    const int b    = (blockIdx.x >> 9) & 1;
    const int blk  = blockIdx.x & 511;
    // lat-fast swizzle: consecutive blocks span different lats -> balanced
    // skip-fraction (duration) mix per CU, smaller tail.
    const int lat  = blk & 63;
    const int lon0 = ((blk >> 6) & 7) * TG;
    const int sbase = half * (NSTA / 2);

    const float latv = -90.0f + (180.0f / 63.0f) * (float)lat;
    const float LIM  = (float)TABN - 0.5f;
    const float CELL = TABW / (float)TABN;

    // even table MINUS end-cell value: clamped gather contributes exactly 0
    // (end-cell constant folded into lin.w by cvt prep) -> skip path is EXACT.
    const float gend = gelu_ref(-LIM * CELL);
#pragma unroll
    for (int k = tid; k < TABN; k += 256) {
        float x = ((float)k + 0.5f) * CELL;
        gtab[k] = gelu_ref(-x) - gend;
    }
    if (tid < 32) {
        wpk[tid] = *(const float4*)&wbuf[tid * 8];
        w2t[tid] = wbuf[tid * 8 + 4];
        w2h[tid] = wbuf[tid * 8 + 5];
    }
    const f32x4 lin = *(const f32x4*)&wbuf[256];

    // phase A mapping: thread -> (grid col gA, station group sgrp of 8)
    const int gA   = tid & (TG - 1);
    const int sgrp = tid >> 4;             // 0..15
    const float lonvA = -180.0f + (360.0f / 127.0f) * (float)(lon0 + gA);

    // phase C mapping: wave w owns d in [w*64, w*64+64)
    const int lane = tid & 63;
    const int wv   = tid >> 6;

    f32x4 acc[4];
#pragma unroll
    for (int t = 0; t < 4; ++t) acc[t] = (f32x4){0.0f, 0.0f, 0.0f, 0.0f};

    const float* cbase = coords + (size_t)b * NSTA * 3;
    const float* mbase = maskp  + (size_t)b * NSTA;
    const _Float16* fhb = fhi + (size_t)b * HID * NSTA;
    const _Float16* flb = flo + (size_t)b * HID * NSTA;

    float m_A = -1.0e30f;   // running max for lon gA (per-thread, consistent blockwide)
    float l_t = 0.0f;       // running denom partial for (gA, sgrp) slice

    __syncthreads();   // gtab / weights visible

// phase C for chunk cc (reads fragA[cc&1] + alphaS of chunk cc; both were
// written before the most recent bar2, so safe to run pre-bar1).
#define PHASE_C(cc)                                                                \
    {                                                                              \
        const f32x4 alv = *(const f32x4*)&alphaS[(lane >> 4) * 4];                 \
        _Pragma("unroll")                                                          \
        for (int t = 0; t < 4; ++t) acc[t] = acc[t] * alv;                         \
        const int srow = sbase + (cc) * SC + ((lane >> 4) * 8);                    \
        const int dbase = wv * 64 + (lane & 15);                                   \
        _Pragma("unroll")                                                          \
        for (int kc = 0; kc < 4; ++kc) {                                           \
            f16x8 ah   = fragAh[(cc) & 1][(kc << 6) + lane];                       \
            f16x8 al16 = fragAl[(cc) & 1][(kc << 6) + lane];                       \
            _Pragma("unroll")                                                      \
            for (int t = 0; t < 4; ++t) {                                          \
                const size_t off = (size_t)(dbase + t * 16) * NSTA + srow + kc * 32; \
                f16x8 bh = *(const f16x8*)(fhb + off);                             \
                f16x8 bl = *(const f16x8*)(flb + off);                             \
                acc[t] = __builtin_amdgcn_mfma_f32_16x16x32_f16(ah, bh, acc[t], 0, 0, 0); \
                acc[t] = __builtin_amdgcn_mfma_f32_16x16x32_f16(ah, bl, acc[t], 0, 0, 0); \
                acc[t] = __builtin_amdgcn_mfma_f32_16x16x32_f16(al16, bh, acc[t], 0, 0, 0); \
            }                                                                      \
        }                                                                          \
    }

    for (int c = 0; c < NCH; ++c) {
        const int s0 = sbase + c * SC;

        // ---- Phase C for previous chunk, issued here so its VMEM latency and
        // MFMA issue overlap phase A's VALU work below.
        if (c) PHASE_C(c - 1)

        // ---- Phase A: scores for 8 stations (4 f32x2 pairs) at grid col gA.
        f32x2 dist2[4], dla2[4], dlo2[4], v2[4];
#pragma unroll
        for (int p = 0; p < 4; ++p) {
            const int s = s0 + sgrp * 8 + p * 2;
            float a0 = cbase[(size_t)s * 3 + 0] - latv;
            float o0 = cbase[(size_t)s * 3 + 1] - lonvA;
            float a1 = cbase[(size_t)s * 3 + 3] - latv;
            float o1 = cbase[(size_t)s * 3 + 4] - lonvA;
            dla2[p] = (f32x2){a0, a1};
            dlo2[p] = (f32x2){o0, o1};
            f32x2 dd = dla2[p] * dla2[p] + dlo2[p] * dlo2[p] + 1e-6f;
            dist2[p] = (f32x2){sqrtf(dd.x), sqrtf(dd.y)};
            v2[p] = dist2[p] * lin.x + (dla2[p] * lin.y + (dlo2[p] * lin.z + lin.w));
        }
#pragma unroll 2
        for (int j = 0; j < 32; ++j) {
            const float4 wq = wpk[j];
            const float  wy = w2h[j];
            f32x2 pre[4];
            float amin;
            {
                // packed pre (3 v_pk_fma each); scalar |pre| terms use free |src| mods
                pre[0] = dist2[0] * wq.x + (dla2[0] * wq.y + (dlo2[0] * wq.z + wq.w));
                pre[1] = dist2[1] * wq.x + (dla2[1] * wq.y + (dlo2[1] * wq.z + wq.w));
                pre[2] = dist2[2] * wq.x + (dla2[2] * wq.y + (dlo2[2] * wq.z + wq.w));
                pre[3] = dist2[3] * wq.x + (dla2[3] * wq.y + (dlo2[3] * wq.z + wq.w));
                amin = fminf(fabsf(pre[0].x), fabsf(pre[0].y));
#pragma unroll
                for (int p = 0; p < 4; ++p) {
                    v2[p].x = fmaf(wy, fabsf(pre[p].x), v2[p].x);
                    v2[p].y = fmaf(wy, fabsf(pre[p].y), v2[p].y);
                    if (p) amin = fminf(amin, fminf(fabsf(pre[p].x), fabsf(pre[p].y)));
                }
            }
            // far-field skip: if EVERY lane's 8 stations are clamped, the table
            // term is exactly 0 (gtab' end cell == 0) -> skip the gathers.
            if (__any(amin < LIM)) {
                const float w2 = w2t[j];
#pragma unroll
                for (int p = 0; p < 4; ++p) {
                    float a0 = fminf(fabsf(pre[p].x), LIM);
                    float a1 = fminf(fabsf(pre[p].y), LIM);
                    v2[p].x = fmaf(w2, gtab[(unsigned)a0], v2[p].x);
                    v2[p].y = fmaf(w2, gtab[(unsigned)a1], v2[p].y);
                }
            }
        }
        float lmax = -3.0e38f;
        float v[8];
#pragma unroll
        for (int p = 0; p < 4; ++p) {
            const int s = s0 + sgrp * 8 + p * 2;
#pragma unroll
            for (int e = 0; e < 2; ++e) {
                float x  = e ? v2[p].y : v2[p].x;
                float ax = fabsf(x);
                float ee = __builtin_amdgcn_exp2f(-ax * LOG2E);
                float sp = fmaxf(x, 0.0f) + __builtin_amdgcn_logf(1.0f + ee) * LN2;
                float vv = sp * mbase[s + e];
                v[p * 2 + e] = vv;
                lmax = fmaxf(lmax, vv);
            }
        }
        // wave-reduce over the wave's 4 sgrps (lane bits 4..5), publish per lon
        float wm = lmax;
        wm = fmaxf(wm, __shfl_xor(wm, 16, 64));
        wm = fmaxf(wm, __shfl_xor(wm, 32, 64));
        if (lane < TG) wmaxW[wv][lane] = wm;
        __syncthreads();   // bar1: wmaxW ready; prev C done with fragA/alphaS

        // every thread: chunk max for its own lon -> running max + alpha (consistent)
        float cmx = fmaxf(fmaxf(wmaxW[0][gA], wmaxW[1][gA]),
                          fmaxf(wmaxW[2][gA], wmaxW[3][gA]));
        float mnew  = fmaxf(m_A, cmx);
        float alpha = __builtin_amdgcn_exp2f((m_A - mnew) * LOG2E);
        m_A = mnew;
        if (tid < TG) alphaS[tid] = alpha;   // tid<16 has gA==tid

        // ---- B2: p = exp2(v-m) -> f16 hi+lo in A-frag layout; local denom update
        {
            float ps = 0.0f;
            f16x8 fh, fl;
#pragma unroll
            for (int i = 0; i < 8; ++i) {
                float p = __builtin_amdgcn_exp2f((v[i] - mnew) * LOG2E);
                _Float16 h = (_Float16)p;
                fh[i] = h;
                fl[i] = (_Float16)(p - (float)h);
                ps += p;
            }
            const int idx = ((sgrp >> 2) << 6) + (((sgrp & 3) << 4) | gA);
            fragAh[c & 1][idx] = fh;
            fragAl[c & 1][idx] = fl;
            l_t = fmaf(l_t, alpha, ps);
        }
        __syncthreads();   // bar2: fragA[c&1] + alphaS ready for next iter's C
    }

    // ---- drain: phase C for the last chunk
    PHASE_C(NCH - 1)
#undef PHASE_C

    // ---- epilogue: reduce l across sgrps; write UNNORMALIZED partials + (m,l)
    lred[sgrp][gA] = l_t;
    __syncthreads();
    {
        float* dst = half ? acc1 : out;
        const int m0 = (lane >> 4) * 4;
        const size_t gbase = (size_t)lat * NLON + lon0 + m0;
#pragma unroll
        for (int t = 0; t < 4; ++t) {
            const int d = wv * 64 + t * 16 + (lane & 15);
            *reinterpret_cast<f32x4*>(dst + ((size_t)(b * HID + d)) * NG + gbase) = acc[t];
        }
        if (tid < TG) {
            float t = 0.0f;
#pragma unroll
            for (int k = 0; k < TG; ++k) t += lred[k][tid];
            ml[((half << 1) + b) * NG + lat * NLON + lon0 + tid] = make_float2(m_A, t);
        }
    }
}

// ---- Combine kernel: out = (acc0*e^{m0-M} + acc1*e^{m1-M}) / (l0*e^{m0-M} + l1*e^{m1-M})
__global__ __launch_bounds__(256)
void comb_kernel(float* __restrict__ out, const float* __restrict__ acc1,
                 const float2* __restrict__ ml) {
    const int x    = blockIdx.x;          // 1024 = b(2) * lat(64) * dseg(8)
    const int b    = x >> 9;
    const int lat  = (x >> 3) & 63;
    const int dseg = x & 7;               // 32 d each
    const int lon  = threadIdx.x & 127;
    const int dsub = threadIdx.x >> 7;    // 0..1
    const int g    = lat * NLON + lon;

    const float2 p0 = ml[b * NG + g];
    const float2 p1 = ml[(2 + b) * NG + g];
    const float M  = fmaxf(p0.x, p1.x);
    float s0 = __builtin_amdgcn_exp2f((p0.x - M) * LOG2E);
    float s1 = __builtin_amdgcn_exp2f((p1.x - M) * LOG2E);
    const float rl = 1.0f / fmaf(p0.y, s0, p1.y * s1);
    s0 *= rl; s1 *= rl;

#pragma unroll 4
    for (int k = 0; k < 16; ++k) {
        const int d = dseg * 32 + dsub + k * 2;
        const size_t o = ((size_t)(b * HID + d)) * NG + g;
        out[o] = fmaf(out[o], s0, acc1[o] * s1);
    }
}

extern "C" void kernel_launch(void* const* d_in, const int* in_sizes, int n_in,
                              void* d_out, int out_size, void* d_ws, size_t ws_size,
                              hipStream_t stream) {
    const float* feats  = (const float*)d_in[0];
    const float* coords = (const float*)d_in[1];
    const float* maskp  = (const float*)d_in[2];
    const float* W1     = (const float*)d_in[3];
    const float* b1     = (const float*)d_in[4];
    const float* W2     = (const float*)d_in[5];
    const float* b2     = (const float*)d_in[6];
    float* out          = (float*)d_out;

    // workspace map:
    //   fhi  [2][256][1024] f16 : 1 MB
    //   flo  [2][256][1024] f16 : 1 MB
    //   acc1 [2][256][8192] f32 : 16 MB   (half-1 partial; half-0 goes to d_out)
    //   ml   [2][2][8192] float2: 256 KB
    //   wbuf 260 floats (packed weights)
    _Float16* fhi = (_Float16*)d_ws;
    _Float16* flo = fhi + (size_t)2 * HID * NSTA;
    float*  acc1 = (float*)((char*)d_ws + (size_t)2 * 1048576);
    float2* ml   = (float2*)((char*)d_ws + (size_t)2 * 1048576 + (size_t)2 * HID * NG * 4);
    float*  wbuf = (float*)((char*)d_ws + (size_t)2 * 1048576 + (size_t)2 * HID * NG * 4 + 262144);

    hipLaunchKernelGGL(cvt_kernel, dim3(257), dim3(256), 0, stream,
                       feats, W1, b1, W2, b2, fhi, flo, wbuf);
    hipLaunchKernelGGL(s2g_kernel, dim3(2048), dim3(256), 0, stream,
                       coords, maskp, wbuf, fhi, flo, out, acc1, ml);
    hipLaunchKernelGGL(comb_kernel, dim3(1024), dim3(256), 0, stream, out, acc1, ml);
}